// Round 2
// baseline (320.907 us; speedup 1.0000x reference)
//
#include <hip/hip_runtime.h>
#include <hip/hip_bf16.h>

#define NN 200000
#define D 128
#define P 4096
#define R 4
#define T 3
#define K 16

__device__ __forceinline__ float bf2f(unsigned int u) {
    union { unsigned int i; float f; } c;
    c.i = u << 16;
    return c.f;
}
__device__ __forceinline__ unsigned short f2bf(float x) {  // RNE
    union { float f; unsigned int i; } c; c.f = x;
    unsigned int r = c.i + 0x7FFFu + ((c.i >> 16) & 1u);
    return (unsigned short)(r >> 16);
}
// scalar element load, dtype-flagged
__device__ __forceinline__ float ldE(const void* p, size_t i, int f32) {
    return f32 ? ((const float*)p)[i] : bf2f(((const unsigned short*)p)[i]);
}
// 8 consecutive elements (elem_off multiple of 8), dtype-flagged
__device__ __forceinline__ void ld8(const void* p, size_t off, int f32, float* o) {
    if (f32) {
        const float* q = (const float*)p + off;
        float4 a = *(const float4*)q;
        float4 b = *(const float4*)(q + 4);
        o[0]=a.x; o[1]=a.y; o[2]=a.z; o[3]=a.w;
        o[4]=b.x; o[5]=b.y; o[6]=b.z; o[7]=b.w;
    } else {
        uint4 r = *(const uint4*)((const unsigned short*)p + off);
        o[0]=bf2f(r.x & 0xffffu); o[1]=bf2f(r.x >> 16);
        o[2]=bf2f(r.y & 0xffffu); o[3]=bf2f(r.y >> 16);
        o[4]=bf2f(r.z & 0xffffu); o[5]=bf2f(r.z >> 16);
        o[6]=bf2f(r.w & 0xffffu); o[7]=bf2f(r.w >> 16);
    }
}

// Kernel A: detect whether float tensors are fp32 (flag=1) or bf16 (flag=0).
// Even-index ushorts of a bf16 buffer are genuine bf16 of N(0,1) (small exp);
// of an fp32 buffer they are random mantissa bits (uniform exponent).
__global__ void detect_dtype(const unsigned short* __restrict__ emb, int* __restrict__ flag) {
    int tid = threadIdx.x;   // 64 threads
    int bad = 0;
    #pragma unroll
    for (int i = 0; i < 4; ++i) {
        unsigned short u = emb[(size_t)(tid * 4 + i) * 2 * 97]; // even indices, spread out
        unsigned int e = (u >> 7) & 0xFFu;                      // bf16 exponent field
        if (e >= 147u) bad = 1;                                 // |x| >= ~1e6 (or inf/nan)
    }
    int any_bad = __any(bad);
    if (tid == 0) *flag = any_bad ? 1 : 0;
}

// Kernel B: v_t = W_phi[t] @ zn ; u_t = W_phi[t] @ zs  (T x D each)
__global__ void precompute_vu(const void* __restrict__ W_phi,
                              const void* __restrict__ W_zeta,
                              const int* __restrict__ flag,
                              float* __restrict__ ws_v, float* __restrict__ ws_u) {
    const int f32 = *flag;
    const int t = blockIdx.x;          // 0..T-1
    const int d = threadIdx.x;         // 0..D-1
    const size_t rb = (size_t)(t * D + d) * D;
    float av = 0.f, au = 0.f;
    for (int e = 0; e < D; e += 8) {
        float w[8], zn[8], zs[8];
        ld8(W_phi, rb + e, f32, w);
        ld8(W_zeta, e, f32, zn);
        ld8(W_zeta, D + e, f32, zs);
        #pragma unroll
        for (int q = 0; q < 8; ++q) { av += w[q] * zn[q]; au += w[q] * zs[q]; }
    }
    ws_v[t * D + d] = av;
    ws_u[t * D + d] = au;
}

// Main fused kernel: one block per pair p.
__global__ __launch_bounds__(256, 4) void fused_kernel(
    const void* __restrict__ emb,               // (N,D) bf16 or fp32
    const int* __restrict__ pairs,              // (P,2)
    const int* __restrict__ types,              // (N,)
    const int* __restrict__ nbr,                // (P,2,R,K)
    const void* __restrict__ dlt,               // (P,2,R,K)
    const void* __restrict__ W_beta_w,          // (R,D,D)
    const void* __restrict__ W_beta_b,          // (R,D)
    const float* __restrict__ ws_v,             // (T,D) fp32
    const float* __restrict__ ws_u,             // (T,D) fp32
    const int* __restrict__ flag,
    void* __restrict__ out)                     // (P,D) bf16 or fp32
{
    __shared__ __align__(16) unsigned short rows[128 * D]; // 32 KB, canonical bf16
    __shared__ __align__(16) float vsh[T * D];
    __shared__ float en_sh[128];
    __shared__ float al_sh[128];
    __shared__ float es_sh[2];
    __shared__ float gbuf[4 * D];
    __shared__ float ybuf[4 * D];

    const int f32  = *flag;
    const int p    = blockIdx.x;
    const int tid  = threadIdx.x;
    const int w    = tid >> 6;     // wave 0..3
    const int lane = tid & 63;

    for (int i = tid; i < T * D; i += 256) vsh[i] = ws_v[i];

    // e_s for s=0,1 (waves 0 and 1): emb[pair] . u_type
    if (w < 2) {
        int n = pairs[p * 2 + w];
        int t = types[n];
        size_t base = (size_t)n * D + 2 * lane;
        float part = ldE(emb, base,     f32) * ws_u[t * D + 2 * lane]
                   + ldE(emb, base + 1, f32) * ws_u[t * D + 2 * lane + 1];
        #pragma unroll
        for (int off = 32; off >= 1; off >>= 1) part += __shfl_xor(part, off, 64);
        if (lane == 0) es_sh[w] = part;
    }
    __syncthreads();

    // Phase 2: gather 128 neighbor rows, compute e_n, stash bf16 rows in LDS.
    {
        const int rsub = lane >> 4;     // 0..3
        const int li   = lane & 15;     // 8-elem chunk within row
        const int base = p * 2 * R * K;
        #pragma unroll
        for (int i = 0; i < 8; ++i) {
            int j  = w * 32 + i * 4 + rsub;        // 0..127
            int nb = nbr[base + j];
            int t  = types[nb];
            float rv[8];
            ld8(emb, (size_t)nb * D + li * 8, f32, rv);
            const float* vp = vsh + t * D + li * 8;
            float part = 0.f;
            #pragma unroll
            for (int q = 0; q < 8; ++q) part += rv[q] * vp[q];
            uint4 pk;
            pk.x = (unsigned int)f2bf(rv[0]) | ((unsigned int)f2bf(rv[1]) << 16);
            pk.y = (unsigned int)f2bf(rv[2]) | ((unsigned int)f2bf(rv[3]) << 16);
            pk.z = (unsigned int)f2bf(rv[4]) | ((unsigned int)f2bf(rv[5]) << 16);
            pk.w = (unsigned int)f2bf(rv[6]) | ((unsigned int)f2bf(rv[7]) << 16);
            *(uint4*)(rows + j * D + li * 8) = pk;
            #pragma unroll
            for (int off = 8; off >= 1; off >>= 1) part += __shfl_xor(part, off, 64);
            if (li == 0) en_sh[j] = part;
        }
    }
    __syncthreads();

    // Phase 3: softmax over K for each of 8 (s,r) groups.
    if (tid < 8) {
        int g = tid, s = g >> 2;
        float es = es_sh[s];
        size_t base = (size_t)p * 2 * R * K + g * K;
        float ev[K];
        float mx = -1e30f;
        #pragma unroll
        for (int k = 0; k < K; ++k) {
            float dt = ldE(dlt, base + k, f32);
            float e  = (en_sh[g * K + k] + es) * __expf(-dt);
            ev[k] = e;
            mx = fmaxf(mx, e);
        }
        float sum = 0.f;
        #pragma unroll
        for (int k = 0; k < K; ++k) { ev[k] = __expf(ev[k] - mx); sum += ev[k]; }
        float inv = 1.f / sum;
        #pragma unroll
        for (int k = 0; k < K; ++k) al_sh[g * K + k] = ev[k] * inv;
    }
    __syncthreads();

    // Phase 4: g_r[d] = sum_s sum_k alpha * row[d]; wave w -> r=w.
    {
        float a0 = 0.f, a1 = 0.f;
        #pragma unroll
        for (int s = 0; s < 2; ++s) {
            int gidx = (s * 4 + w) * K;
            #pragma unroll
            for (int k = 0; k < K; ++k) {
                float al = al_sh[gidx + k];
                int rb = (gidx + k) * D;
                a0 += al * bf2f(rows[rb + lane]);
                a1 += al * bf2f(rows[rb + 64 + lane]);
            }
        }
        gbuf[w * D + lane]      = a0;
        gbuf[w * D + 64 + lane] = a1;
    }
    __syncthreads();

    // Phase 5: y_r[e] = sum_d g_r[d] * W_beta_w[r,d,e]; wave w -> r=w.
    {
        const size_t Wb = (size_t)w * D * D + 2 * lane;
        float y0 = 0.f, y1 = 0.f;
        #pragma unroll 4
        for (int d = 0; d < D; ++d) {
            float gd = gbuf[w * D + d];
            size_t ix = Wb + (size_t)d * D;
            y0 += gd * ldE(W_beta_w, ix,     f32);
            y1 += gd * ldE(W_beta_w, ix + 1, f32);
        }
        ybuf[w * D + 2 * lane]     = y0;
        ybuf[w * D + 2 * lane + 1] = y1;
    }
    __syncthreads();

    // Phase 6: x = (sum_r y_r + 2*sum_r b_r)/8 ; sigmoid ; store per dtype.
    if (tid < D) {
        int e = tid;
        float x = ybuf[e] + ybuf[D + e] + ybuf[2 * D + e] + ybuf[3 * D + e];
        float bs = 0.f;
        #pragma unroll
        for (int r = 0; r < R; ++r) bs += ldE(W_beta_b, r * D + e, f32);
        x = (x + 2.f * bs) * 0.125f;
        float o = 1.f / (1.f + __expf(-x));
        size_t oi = (size_t)p * D + e;
        if (f32) ((float*)out)[oi] = o;
        else     ((unsigned short*)out)[oi] = f2bf(o);
    }
}

extern "C" void kernel_launch(void* const* d_in, const int* in_sizes, int n_in,
                              void* d_out, int out_size, void* d_ws, size_t ws_size,
                              hipStream_t stream) {
    const void* emb    = d_in[0];
    const int*  pairs  = (const int*)d_in[1];
    const int*  types  = (const int*)d_in[2];
    const int*  nbr    = (const int*)d_in[3];
    const void* dlt    = d_in[4];
    const void* W_phi  = d_in[5];
    const void* W_zeta = d_in[6];
    const void* W_bw   = d_in[7];
    const void* W_bb   = d_in[8];

    int*   flag = (int*)d_ws;                    // [0]
    float* ws_v = (float*)d_ws + 64;             // T*D floats
    float* ws_u = ws_v + T * D;                  // T*D floats

    detect_dtype<<<dim3(1), dim3(64), 0, stream>>>((const unsigned short*)emb, flag);
    precompute_vu<<<dim3(T), dim3(D), 0, stream>>>(W_phi, W_zeta, flag, ws_v, ws_u);
    fused_kernel<<<dim3(P), dim3(256), 0, stream>>>(emb, pairs, types, nbr, dlt,
                                                    W_bw, W_bb, ws_v, ws_u, flag, d_out);
}

// Round 3
// 248.011 us; speedup vs baseline: 1.2939x; 1.2939x over previous
//
#include <hip/hip_runtime.h>
#include <hip/hip_bf16.h>

#define NN 200000
#define D 128
#define P 4096
#define R 4
#define T 3
#define K 16

__device__ __forceinline__ float bf2f(unsigned int u) {
    union { unsigned int i; float f; } c;
    c.i = u << 16;
    return c.f;
}
__device__ __forceinline__ unsigned short f2bf(float x) {  // RNE
    union { float f; unsigned int i; } c; c.f = x;
    unsigned int r = c.i + 0x7FFFu + ((c.i >> 16) & 1u);
    return (unsigned short)(r >> 16);
}
__device__ __forceinline__ float ldE(const void* p, size_t i, int f32) {
    return f32 ? ((const float*)p)[i] : bf2f(((const unsigned short*)p)[i]);
}
__device__ __forceinline__ void ld8(const void* p, size_t off, int f32, float* o) {
    if (f32) {
        const float* q = (const float*)p + off;
        float4 a = *(const float4*)q;
        float4 b = *(const float4*)(q + 4);
        o[0]=a.x; o[1]=a.y; o[2]=a.z; o[3]=a.w;
        o[4]=b.x; o[5]=b.y; o[6]=b.z; o[7]=b.w;
    } else {
        uint4 r = *(const uint4*)((const unsigned short*)p + off);
        o[0]=bf2f(r.x & 0xffffu); o[1]=bf2f(r.x >> 16);
        o[2]=bf2f(r.y & 0xffffu); o[3]=bf2f(r.y >> 16);
        o[4]=bf2f(r.z & 0xffffu); o[5]=bf2f(r.z >> 16);
        o[6]=bf2f(r.w & 0xffffu); o[7]=bf2f(r.w >> 16);
    }
}

// Kernel A: dtype sniffing (bf16 vs fp32) — validated in round 2 (bf16 chosen, passed).
__global__ void detect_dtype(const unsigned short* __restrict__ emb, int* __restrict__ flag) {
    int tid = threadIdx.x;   // 64 threads
    int bad = 0;
    #pragma unroll
    for (int i = 0; i < 4; ++i) {
        unsigned short u = emb[(size_t)(tid * 4 + i) * 2 * 97];
        unsigned int e = (u >> 7) & 0xFFu;
        if (e >= 147u) bad = 1;
    }
    int any_bad = __any(bad);
    if (tid == 0) *flag = any_bad ? 1 : 0;
}

// Kernel B: v_t = W_phi[t] @ zn ; u_t = W_phi[t] @ zs  (T x D each)
__global__ void precompute_vu(const void* __restrict__ W_phi,
                              const void* __restrict__ W_zeta,
                              const int* __restrict__ flag,
                              float* __restrict__ ws_v, float* __restrict__ ws_u) {
    const int f32 = *flag;
    const int t = blockIdx.x;
    const int d = threadIdx.x;
    const size_t rb = (size_t)(t * D + d) * D;
    float av = 0.f, au = 0.f;
    for (int e = 0; e < D; e += 8) {
        float w[8], zn[8], zs[8];
        ld8(W_phi, rb + e, f32, w);
        ld8(W_zeta, e, f32, zn);
        ld8(W_zeta, D + e, f32, zs);
        #pragma unroll
        for (int q = 0; q < 8; ++q) { av += w[q] * zn[q]; au += w[q] * zs[q]; }
    }
    ws_v[t * D + d] = av;
    ws_u[t * D + d] = au;
}

// Kernel C: per-node scores c[n]=emb[n].v_{t(n)}, c2[n]=emb[n].u_{t(n)}.
// Streaming 51 MB coalesced; removes types-gather + per-row dot from the hot kernel.
__global__ __launch_bounds__(256) void precompute_c(
    const void* __restrict__ emb, const int* __restrict__ types,
    const float* __restrict__ ws_v, const float* __restrict__ ws_u,
    const int* __restrict__ flag,
    float* __restrict__ c, float* __restrict__ c2)
{
    __shared__ float vsh[T * D], ush[T * D];
    const int f32 = *flag;
    const int tid = threadIdx.x;
    for (int i = tid; i < T * D; i += 256) { vsh[i] = ws_v[i]; ush[i] = ws_u[i]; }
    __syncthreads();
    const int w = tid >> 6, l = tid & 63;
    const int grp = l >> 4, ch = l & 15;          // 16 lanes per node
    const int n = blockIdx.x * 16 + w * 4 + grp;
    if (n >= NN) return;
    const int t = types[n];
    float rv[8]; ld8(emb, (size_t)n * D + ch * 8, f32, rv);
    const float* vp = vsh + t * D + ch * 8;
    const float* up = ush + t * D + ch * 8;
    float a = 0.f, b = 0.f;
    #pragma unroll
    for (int q = 0; q < 8; ++q) { a += rv[q] * vp[q]; b += rv[q] * up[q]; }
    #pragma unroll
    for (int off = 1; off <= 8; off <<= 1) {
        a += __shfl_xor(a, off, 64);
        b += __shfl_xor(b, off, 64);
    }
    if (ch == 0) { c[n] = a; c2[n] = b; }
}

// Main fused kernel: one block per pair. Register-resident row gather, no row LDS.
__global__ __launch_bounds__(256, 4) void fused_kernel(
    const void* __restrict__ emb,               // (N,D)
    const int* __restrict__ pairs,              // (P,2)
    const int* __restrict__ nbr,                // (P,2,R,K)
    const void* __restrict__ dlt,               // (P,2,R,K)
    const void* __restrict__ W_beta_w,          // (R,D,D)
    const void* __restrict__ W_beta_b,          // (R,D)
    const float* __restrict__ c,                // (N,)
    const float* __restrict__ c2,               // (N,)
    const int* __restrict__ flag,
    void* __restrict__ out)                     // (P,D)
{
    __shared__ float esc[128];                  // e scores, then alpha in place
    __shared__ __align__(16) float gbuf[4 * D];
    __shared__ __align__(16) float ybuf[4 * D];

    const int f32  = *flag;
    const int p    = blockIdx.x;
    const int tid  = threadIdx.x;
    const int w    = tid >> 6;                  // wave = r
    const int l    = tid & 63;
    const int rsub = l >> 4;                    // row-in-quad / d-quarter
    const int ch   = l & 15;                    // 8-elem chunk
    const int base = p * 2 * R * K;

    // --- Prefetch (bf16 fast path): issue all row gathers NOW; they drain
    // behind the score/softmax phases. jj = s*64 + w*16 + k, k=(i&3)*4+rsub.
    int  nbv[8];
    uint4 rb[8];
    if (!f32) {
        const unsigned short* eu = (const unsigned short*)emb;
        #pragma unroll
        for (int i = 0; i < 8; ++i) {
            int jj = ((i >> 2) * 64) + w * 16 + (i & 3) * 4 + rsub;
            nbv[i] = nbr[base + jj];
        }
        #pragma unroll
        for (int i = 0; i < 8; ++i)
            rb[i] = *(const uint4*)(eu + (size_t)nbv[i] * D + ch * 8);
    }

    // --- Phase A: scores e = (c[nb] + c2[pair_s]) * exp(-dt)
    if (tid < 128) {
        int s  = tid >> 6;
        int nb = nbr[base + tid];
        float ce = c[nb];
        float cs = c2[pairs[p * 2 + s]];
        float dt = ldE(dlt, (size_t)base + tid, f32);
        esc[tid] = (ce + cs) * __expf(-dt);
    }
    __syncthreads();

    // --- Phase B: softmax over K per group, in place
    if (tid < 8) {
        float ev[K];
        float mx = -1e30f;
        #pragma unroll
        for (int k = 0; k < K; ++k) { ev[k] = esc[tid * K + k]; mx = fmaxf(mx, ev[k]); }
        float sum = 0.f;
        #pragma unroll
        for (int k = 0; k < K; ++k) { ev[k] = __expf(ev[k] - mx); sum += ev[k]; }
        float inv = 1.f / sum;
        #pragma unroll
        for (int k = 0; k < K; ++k) esc[tid * K + k] = ev[k] * inv;
    }
    __syncthreads();

    // --- Phase C: g_r[d] = sum_{s,k} alpha * emb[nb][d]  (wave w -> r=w)
    float acc[8] = {0.f,0.f,0.f,0.f,0.f,0.f,0.f,0.f};
    if (!f32) {
        float al[8];
        #pragma unroll
        for (int i = 0; i < 8; ++i) {
            int jj = ((i >> 2) * 64) + w * 16 + (i & 3) * 4 + rsub;
            al[i] = esc[jj];
        }
        #pragma unroll
        for (int i = 0; i < 8; ++i) {
            float a = al[i];
            acc[0] += a * bf2f(rb[i].x & 0xffffu); acc[1] += a * bf2f(rb[i].x >> 16);
            acc[2] += a * bf2f(rb[i].y & 0xffffu); acc[3] += a * bf2f(rb[i].y >> 16);
            acc[4] += a * bf2f(rb[i].z & 0xffffu); acc[5] += a * bf2f(rb[i].z >> 16);
            acc[6] += a * bf2f(rb[i].w & 0xffffu); acc[7] += a * bf2f(rb[i].w >> 16);
        }
    } else {
        #pragma unroll
        for (int i = 0; i < 8; ++i) {
            int jj = ((i >> 2) * 64) + w * 16 + (i & 3) * 4 + rsub;
            int nb = nbr[base + jj];
            float a = esc[jj];
            float rv[8]; ld8(emb, (size_t)nb * D + ch * 8, 1, rv);
            #pragma unroll
            for (int q = 0; q < 8; ++q) acc[q] += a * rv[q];
        }
    }
    #pragma unroll
    for (int q = 0; q < 8; ++q) {
        acc[q] += __shfl_xor(acc[q], 16, 64);
        acc[q] += __shfl_xor(acc[q], 32, 64);
    }
    if (rsub == 0) {
        *(float4*)(gbuf + w * D + ch * 8)     = make_float4(acc[0], acc[1], acc[2], acc[3]);
        *(float4*)(gbuf + w * D + ch * 8 + 4) = make_float4(acc[4], acc[5], acc[6], acc[7]);
    }
    __syncthreads();

    // --- Phase D: y_r[e] = sum_d g_r[d] * W[r,d,e]; 16B/lane coalesced loads.
    {
        const int dq = rsub;                     // d-quarter 0..3
        float y[8] = {0.f,0.f,0.f,0.f,0.f,0.f,0.f,0.f};
        #pragma unroll 4
        for (int dd = 0; dd < 32; ++dd) {
            int d = dq * 32 + dd;
            float gd = gbuf[w * D + d];
            float wb[8]; ld8(W_beta_w, ((size_t)(w * D + d)) * D + ch * 8, f32, wb);
            #pragma unroll
            for (int q = 0; q < 8; ++q) y[q] += gd * wb[q];
        }
        #pragma unroll
        for (int q = 0; q < 8; ++q) {
            y[q] += __shfl_xor(y[q], 16, 64);
            y[q] += __shfl_xor(y[q], 32, 64);
        }
        if (dq == 0) {
            *(float4*)(ybuf + w * D + ch * 8)     = make_float4(y[0], y[1], y[2], y[3]);
            *(float4*)(ybuf + w * D + ch * 8 + 4) = make_float4(y[4], y[5], y[6], y[7]);
        }
    }
    __syncthreads();

    // --- Phase E: combine, bias, sigmoid, store
    if (tid < 128) {
        int e = tid;
        float x = ybuf[e] + ybuf[D + e] + ybuf[2 * D + e] + ybuf[3 * D + e];
        float bs = 0.f;
        #pragma unroll
        for (int r = 0; r < R; ++r) bs += ldE(W_beta_b, r * D + e, f32);
        x = (x + 2.f * bs) * 0.125f;
        float o = 1.f / (1.f + __expf(-x));
        size_t oi = (size_t)p * D + e;
        if (f32) ((float*)out)[oi] = o;
        else     ((unsigned short*)out)[oi] = f2bf(o);
    }
}

extern "C" void kernel_launch(void* const* d_in, const int* in_sizes, int n_in,
                              void* d_out, int out_size, void* d_ws, size_t ws_size,
                              hipStream_t stream) {
    const void* emb    = d_in[0];
    const int*  pairs  = (const int*)d_in[1];
    const int*  types  = (const int*)d_in[2];
    const int*  nbr    = (const int*)d_in[3];
    const void* dlt    = d_in[4];
    const void* W_phi  = d_in[5];
    const void* W_zeta = d_in[6];
    const void* W_bw   = d_in[7];
    const void* W_bb   = d_in[8];

    int*   flag = (int*)d_ws;                    // [0..63]
    float* ws_v = (float*)d_ws + 64;             // T*D
    float* ws_u = ws_v + T * D;                  // T*D
    float* c    = (float*)d_ws + 1024;           // N
    float* c2   = c + NN;                        // N  (total ~1.6 MB of d_ws)

    detect_dtype<<<dim3(1), dim3(64), 0, stream>>>((const unsigned short*)emb, flag);
    precompute_vu<<<dim3(T), dim3(D), 0, stream>>>(W_phi, W_zeta, flag, ws_v, ws_u);
    precompute_c<<<dim3((NN + 15) / 16), dim3(256), 0, stream>>>(emb, types, ws_v, ws_u, flag, c, c2);
    fused_kernel<<<dim3(P), dim3(256), 0, stream>>>(emb, pairs, nbr, dlt,
                                                    W_bw, W_bb, c, c2, flag, d_out);
}